// Round 1
// baseline (900.977 us; speedup 1.0000x reference)
//
#include <hip/hip_runtime.h>

// Problem constants (match reference setup_inputs)
#define NB 4096   // batch
#define TT 128    // seq len
#define EE 256    // embed dim
#define HH 64     // head dim

typedef __attribute__((ext_vector_type(8))) short bf16x8;
typedef __attribute__((ext_vector_type(4))) float f32x4;

// LDS strides (in bf16 elements). All multiples of 8 -> 16B-aligned rows,
// and row stride in banks is 32+4 -> +4-bank stagger per row.
#define QK_STRIDE 72    // q,k: [128][72]
#define P_STRIDE  136   // p:   [128][136] (aliases q+k region)
#define VT_STRIDE 136   // vT:  [64][136]

__device__ __forceinline__ unsigned short f2bf(float f) {
  union { float f; unsigned u; } c; c.f = f;
  // round-to-nearest-even bf16
  return (unsigned short)((c.u + 0x7fffu + ((c.u >> 16) & 1u)) >> 16);
}

__device__ __forceinline__ bf16x8 cvt8(f32x4 a, f32x4 b) {
  bf16x8 r;
  r[0] = (short)f2bf(a[0]); r[1] = (short)f2bf(a[1]);
  r[2] = (short)f2bf(a[2]); r[3] = (short)f2bf(a[3]);
  r[4] = (short)f2bf(b[0]); r[5] = (short)f2bf(b[1]);
  r[6] = (short)f2bf(b[2]); r[7] = (short)f2bf(b[3]);
  return r;
}

// Convert Wq|Wk|Wv (each [E][H] fp32) into wt[192][256] bf16, transposed so
// that wt[n][e] = W_{n/64}[e][n%64]. This is the B^T row-contiguous layout the
// MFMA B-operand wants (lane reads 8 consecutive e for fixed n).
__global__ void prep_w(const float* __restrict__ wq, const float* __restrict__ wk,
                       const float* __restrict__ wv, unsigned short* __restrict__ wt) {
  int n = blockIdx.x;    // 0..191
  int e = threadIdx.x;   // 0..255
  const float* w = (n < 64) ? wq : (n < 128) ? wk : wv;
  wt[n * EE + e] = f2bf(w[e * HH + (n & 63)]);
}

__global__ __launch_bounds__(256, 2)
void attn_fused(const float* __restrict__ x, const unsigned short* __restrict__ wt,
                float* __restrict__ out) {
  // Region A: Q[128][72] + K[128][72] bf16 = 36864 B; later reused for P[128][136] (34816 B)
  __shared__ __align__(16) unsigned short sQK[2 * TT * QK_STRIDE];
  // Region B: V^T[64][136] bf16 = 17408 B
  __shared__ __align__(16) unsigned short sVT[HH * VT_STRIDE];
  unsigned short* qbuf = sQK;
  unsigned short* kbuf = sQK + TT * QK_STRIDE;
  unsigned short* pbuf = sQK;  // alias, valid after the post-S barrier

  const int b    = blockIdx.x;
  const int tid  = threadIdx.x;
  const int w    = tid >> 6;    // wave 0..3
  const int lane = tid & 63;
  const int quad = lane >> 4;   // 0..3
  const int l16  = lane & 15;
  const int m0   = 32 * w;      // this wave owns rows [m0, m0+32)

  const float* __restrict__ xb = x + (size_t)b * TT * EE;

  // ---------------- Phase 1: [Q|K|V] = x @ [Wq|Wk|Wv]  (M=128, N=192, K=256)
  // Wave w: m-tiles rows m0, m0+16; all 12 n-tiles. A-frags straight from
  // global fp32 (each x element touched exactly once per block).
  f32x4 acc[12][2];
#pragma unroll
  for (int nt = 0; nt < 12; ++nt)
#pragma unroll
    for (int mt = 0; mt < 2; ++mt)
      acc[nt][mt] = (f32x4){0.f, 0.f, 0.f, 0.f};

  for (int kc = 0; kc < 8; ++kc) {   // K chunks of 32
    bf16x8 afr[2];
#pragma unroll
    for (int mt = 0; mt < 2; ++mt) {
      const float* src = xb + (m0 + 16 * mt + l16) * EE + kc * 32 + quad * 8;
      f32x4 f0 = *(const f32x4*)src;
      f32x4 f1 = *(const f32x4*)(src + 4);
      afr[mt] = cvt8(f0, f1);
    }
#pragma unroll
    for (int nt = 0; nt < 12; ++nt) {
      bf16x8 bfr = *(const bf16x8*)(wt + (nt * 16 + l16) * EE + kc * 32 + quad * 8);
      acc[nt][0] = __builtin_amdgcn_mfma_f32_16x16x32_bf16(afr[0], bfr, acc[nt][0], 0, 0, 0);
      acc[nt][1] = __builtin_amdgcn_mfma_f32_16x16x32_bf16(afr[1], bfr, acc[nt][1], 0, 0, 0);
    }
  }

  // Scatter Q,K ([t][h] row-major) and V^T ([h][t]) to LDS as bf16.
  // C-layout: row = 4*quad + reg, col = l16 within each 16x16 tile.
#pragma unroll
  for (int nt = 0; nt < 12; ++nt) {
    int cg = nt * 16 + l16;          // combined col 0..191
#pragma unroll
    for (int mt = 0; mt < 2; ++mt) {
      int rbase = m0 + 16 * mt + 4 * quad;
#pragma unroll
      for (int r = 0; r < 4; ++r) {
        unsigned short bv = f2bf(acc[nt][mt][r]);
        int row = rbase + r;
        if (nt < 4)      qbuf[row * QK_STRIDE + cg] = bv;
        else if (nt < 8) kbuf[row * QK_STRIDE + (cg - 64)] = bv;
        else             sVT[(cg - 128) * VT_STRIDE + row] = bv;
      }
    }
  }
  __syncthreads();

  // ---------------- Phase 2: S = Q K^T / 8, causal, softmax -> P (bf16, LDS)
  // Wave w: rows [m0, m0+32); only column tiles nt < ntS touch the lower triangle.
  const int ntS = 2 * w + 2;
  f32x4 sacc[8][2];
#pragma unroll
  for (int nt = 0; nt < 8; ++nt)
#pragma unroll
    for (int mt = 0; mt < 2; ++mt)
      sacc[nt][mt] = (f32x4){0.f, 0.f, 0.f, 0.f};

#pragma unroll
  for (int kk = 0; kk < 2; ++kk) {   // head dim 64 -> 2 K-steps
    bf16x8 aq[2];
    aq[0] = *(const bf16x8*)(qbuf + (m0 + l16) * QK_STRIDE + kk * 32 + quad * 8);
    aq[1] = *(const bf16x8*)(qbuf + (m0 + 16 + l16) * QK_STRIDE + kk * 32 + quad * 8);
#pragma unroll
    for (int nt = 0; nt < 8; ++nt) {
      if (nt < ntS) {   // wave-uniform predicate
        bf16x8 bk = *(const bf16x8*)(kbuf + (nt * 16 + l16) * QK_STRIDE + kk * 32 + quad * 8);
        sacc[nt][0] = __builtin_amdgcn_mfma_f32_16x16x32_bf16(aq[0], bk, sacc[nt][0], 0, 0, 0);
        sacc[nt][1] = __builtin_amdgcn_mfma_f32_16x16x32_bf16(aq[1], bk, sacc[nt][1], 0, 0, 0);
      }
    }
  }
  __syncthreads();  // all waves done reading q/k -> region reusable as P

  // Softmax in registers; each (mt,reg) pair is one full row spread across the
  // 16 lanes of this quad (cols l16 + 16*nt).
  const float scale = 0.125f;  // 1/sqrt(64)
#pragma unroll
  for (int mt = 0; mt < 2; ++mt) {
#pragma unroll
    for (int r = 0; r < 4; ++r) {
      int row = m0 + 16 * mt + 4 * quad + r;
      float mx = -3.0e38f;
#pragma unroll
      for (int nt = 0; nt < 8; ++nt) {
        if (nt < ntS) {
          int c = nt * 16 + l16;
          float s = (c <= row) ? sacc[nt][mt][r] * scale : -3.0e38f;
          sacc[nt][mt][r] = s;
          mx = fmaxf(mx, s);
        }
      }
#pragma unroll
      for (int off = 1; off < 16; off <<= 1) mx = fmaxf(mx, __shfl_xor(mx, off, 64));
      float sum = 0.f;
#pragma unroll
      for (int nt = 0; nt < 8; ++nt) {
        if (nt < ntS) {
          float e = __expf(sacc[nt][mt][r] - mx);
          sacc[nt][mt][r] = e;
          sum += e;
        }
      }
#pragma unroll
      for (int off = 1; off < 16; off <<= 1) sum += __shfl_xor(sum, off, 64);
      float inv = 1.0f / sum;
#pragma unroll
      for (int nt = 0; nt < 8; ++nt) {
        if (nt < ntS)
          pbuf[row * P_STRIDE + nt * 16 + l16] = f2bf(sacc[nt][mt][r] * inv);
      }
    }
  }
  // No barrier needed: wave w only reads its own P rows below, and V^T was
  // synced after phase 1.

  // ---------------- Phase 3: out = P @ V   (M=128, N=64, K=128, causal-clipped)
  f32x4 oacc[4][2];
#pragma unroll
  for (int nt = 0; nt < 4; ++nt)
#pragma unroll
    for (int mt = 0; mt < 2; ++mt)
      oacc[nt][mt] = (f32x4){0.f, 0.f, 0.f, 0.f};

  for (int ks = 0; ks <= w; ++ks) {   // only K-tiles that can be nonzero
    bf16x8 ap[2];
    ap[0] = *(const bf16x8*)(pbuf + (m0 + l16) * P_STRIDE + ks * 32 + quad * 8);
    ap[1] = *(const bf16x8*)(pbuf + (m0 + 16 + l16) * P_STRIDE + ks * 32 + quad * 8);
#pragma unroll
    for (int nt = 0; nt < 4; ++nt) {
      bf16x8 bv = *(const bf16x8*)(sVT + (nt * 16 + l16) * VT_STRIDE + ks * 32 + quad * 8);
      oacc[nt][0] = __builtin_amdgcn_mfma_f32_16x16x32_bf16(ap[0], bv, oacc[nt][0], 0, 0, 0);
      oacc[nt][1] = __builtin_amdgcn_mfma_f32_16x16x32_bf16(ap[1], bv, oacc[nt][1], 0, 0, 0);
    }
  }

  float* __restrict__ ob = out + (size_t)b * TT * HH;
#pragma unroll
  for (int mt = 0; mt < 2; ++mt) {
#pragma unroll
    for (int r = 0; r < 4; ++r) {
      int row = m0 + 16 * mt + 4 * quad + r;
#pragma unroll
      for (int nt = 0; nt < 4; ++nt)
        ob[row * HH + nt * 16 + l16] = oacc[nt][mt][r];
    }
  }
}

extern "C" void kernel_launch(void* const* d_in, const int* in_sizes, int n_in,
                              void* d_out, int out_size, void* d_ws, size_t ws_size,
                              hipStream_t stream) {
  const float* x  = (const float*)d_in[0];
  const float* wq = (const float*)d_in[1];
  const float* wk = (const float*)d_in[2];
  const float* wv = (const float*)d_in[3];
  unsigned short* wt = (unsigned short*)d_ws;  // 192*256*2 = 98304 B
  float* outp = (float*)d_out;

  prep_w<<<dim3(192), dim3(256), 0, stream>>>(wq, wk, wv, wt);
  attn_fused<<<dim3(NB), dim3(256), 0, stream>>>(x, wt, outp);
}